// Round 8
// baseline (172628.223 us; speedup 1.0000x reference)
//
#include <hip/hip_runtime.h>

// =====================================================================
// SPINN-style stack LSTM, MI355X.  R8 = R7 main kernel (unchanged,
// correct, ~13ms) + DIAGNOSTIC dispatches to localize the ~20us/step
// stall that survived two barrier-mechanism changes (R6 atomics == R7
// volatile+inv). Diagnostics appear as separate rows in the rocprof
// top-5 table iff their phase dominates:
//   D1 MODE1 2044 steps: barrier-pairs only        (visible <=> >6.4us/pair)
//   D2 MODE2 2044 steps: barriers + staging only   (cold-L1 staging cost)
//   D3 MODE3 4088 steps: work only, no cross-block sync (visible <=> >3.2us/step)
// Diagnostics write only to ws scratch; d_out comes from MODE0 alone.
// =====================================================================

#define NSTEP 511
#define HB 128
#define SQ 256
#define HD 300
#define DW 600
#define TK 64

#define NB 16
#define NE 25           // E blocks per group
#define JPB 12          // j dims per E block
#define DOTS_E 60       // 5 gates * 12 j
#define KE 640          // padded 600
#define UPB 10
#define DOTS_T 40       // 4 gates * 10 units
#define KT2 1000        // padded 964 (900 fused + 64 hh + 36 zero)
#define ASTR 20         // act row stride (floats), 16 slots + pad
#define SLP 820         // act slice pitch = 41 rows * ASTR
#define OUTW 1322

// ---- workspace layout (floats) ----
#define N_WEB 960000            // 25*60*640   E weight slices fp32
#define N_WTB 280000            // 7*40*1000   T fused weight slices fp32
#define N_WTR 97500             // 25*60*65    W_track slices
#define N_TH  16384             // 2*128*64    th double buffer
#define N_STACK 19660800        // 128*256*600
#define N_BAR 1024
#define N_TPK 4096
#define N_BARD 1664             // 3 diag barrier regions (520 each) + slack
#define N_WCT 230400            // WcatT (prep only, overlaps stack)

#define OFF_WEB 0
#define OFF_WTB 960000
#define OFF_WTR 1240000
#define OFF_TH  1337504
#define OFF_STACK 1353888
#define OFF_BAR 21014688
#define OFF_TPK 21015712
#define OFF_BARD 21019808
#define WS_FLOATS 21021472      // <= 21022048 (proven available in R2)
#define OFF_WCT OFF_STACK

// ---- LDS layout (floats) ----
#define L_ACT 0                 // 25 slices * SLP = 20500
#define L_DUMP 20500            // E: 8*EDP=7712 ; T: 25*TDP=16100
#define EDP 964                 // E dump kq pitch (60*16 + 4 skew)
#define TDP 644                 // T dump kq pitch (40*16 + 4 skew)
#define L_WTR 28212             // (E only) 60*65 = 3900
#define L_THL 32112             // 16*65 = 1040
#define L_BRED 33152            // 60(+pad)
#define L_TRW 36600             // 511 ints (+1)
#define L_INT 37112             // 96 ints
#define LDS_FLOATS 37208        // 148832 B (>80KB => 1 block/CU)

__device__ __forceinline__ float sigf(float x) { return 1.0f / (1.0f + __expf(-x)); }

// ---------------------------------------------------------------------
// prep_a: WcatT[256][900], zero th/barrier(+diag)/..., pack transitions.
// ---------------------------------------------------------------------
__global__ void prep_a(const float* __restrict__ Wbuf, const float* __restrict__ Ws1,
                       const float* __restrict__ Ws2, const int* __restrict__ trans,
                       float* __restrict__ ws) {
  int idx = blockIdx.x * 256 + threadIdx.x;
  if (idx < N_WCT) {
    int k = idx % 900;
    int m = idx / 900;
    float v = (k < 300) ? Wbuf[k*256 + m]
            : (k < 600) ? Ws1[(k-300)*256 + m]
                        : Ws2[(k-600)*256 + m];
    ws[OFF_WCT + idx] = v;
    return;
  }
  idx -= N_WCT;
  if (idx < N_TH) { ws[OFF_TH + idx] = 0.0f; return; }
  idx -= N_TH;
  if (idx < N_BAR) { ws[OFF_BAR + idx] = 0.0f; return; }
  idx -= N_BAR;
  if (idx < N_BARD) { ws[OFF_BARD + idx] = 0.0f; return; }
  idx -= N_BARD;
  if (idx < 8*NSTEP) {
    int g = idx / NSTEP, t = idx % NSTEP;
    int w = 0;
    #pragma unroll
    for (int b = 0; b < 16; ++b)
      w |= (trans[(size_t)(g*16 + b)*NSTEP + t] & 1) << b;
    ((int*)(ws + OFF_TPK))[g*NSTEP + t] = w;
  }
}

// ---------------------------------------------------------------------
// prep_b: fp32 transposed weight slices; tracker input projection fused
// with W_ih: WT[col][k<900] = sum_m Wcat[k][m] * W_ih[col][m]  (exact).
// ---------------------------------------------------------------------
__global__ void prep_b(const float* __restrict__ Wih, const float* __restrict__ Whh,
                       const float* __restrict__ Wl, const float* __restrict__ Wr,
                       const float* __restrict__ Wtrk, float* __restrict__ ws) {
  int idx = blockIdx.x * 256 + threadIdx.x;
  if (idx < N_WEB) {
    int k = idx % KE; int rest = idx / KE;
    int dot = rest % DOTS_E; int e = rest / DOTS_E;
    int g = dot / JPB, jj = dot % JPB;
    int col = g*HD + e*JPB + jj;
    float v = 0.0f;
    if (k < 300)      v = Wl[k*1500 + col];
    else if (k < 600) v = Wr[(k-300)*1500 + col];
    ws[OFF_WEB + idx] = v;
    return;
  }
  idx -= N_WEB;
  if (idx < N_WTB) {
    int k = idx % KT2; int rest = idx / KT2;
    int dot = rest % DOTS_T; int tb = rest / DOTS_T;
    int g = dot / UPB, uu = dot % UPB;
    int ucnt = (tb == 6) ? 10 : 9;
    float v = 0.0f;
    if (uu < ucnt) {
      int col = g*TK + tb*9 + uu;
      if (k < 900) {
        const float* wct = ws + OFF_WCT;
        const float* wi  = Wih + col*256;
        float s = 0.0f;
        #pragma unroll 4
        for (int m = 0; m < 256; ++m) s = fmaf(wct[m*900 + k], wi[m], s);
        v = s;
      } else if (k < 964) {
        v = Whh[col*TK + (k - 900)];
      }
    }
    ws[OFF_WTB + idx] = v;
    return;
  }
  idx -= N_WTB;
  if (idx < N_WTR) {
    int k = idx % 65; int rest = idx / 65;
    int dot = rest % DOTS_E; int e = rest / DOTS_E;
    int g = dot / JPB, jj = dot % JPB;
    ws[OFF_WTR + idx] = (k < 64) ? Wtrk[k*1500 + (g*HD + e*JPB + jj)] : 0.0f;
  }
}

// ---------------------------------------------------------------------
// fence-free XCD-local barrier (R2/R7 design). nslot = participants.
// ---------------------------------------------------------------------
__device__ __forceinline__ void xbar(int role, unsigned epoch, int nslot,
                                     volatile unsigned* slots, volatile unsigned* flag,
                                     volatile int* broken) {
  __syncthreads();                      // drains vmcnt on every wave
  if (role == 0) {
    if (threadIdx.x < 64) {
      int lane = threadIdx.x;
      unsigned spins = 0;
      for (;;) {
        if (*broken) break;
        unsigned v = (lane >= 1 && lane < nslot) ? slots[lane] : epoch;
        if (__all(v >= epoch)) break;
        __builtin_amdgcn_s_sleep(1);
        asm volatile("buffer_inv" ::: "memory");
        if (++spins > 2000000u) { if (lane == 0) *broken = 1; break; }
      }
      if (lane == 0) {
        *flag = epoch;
        asm volatile("s_waitcnt vmcnt(0)" ::: "memory");
      }
    }
  } else if (threadIdx.x == 0) {
    slots[role] = epoch;
    asm volatile("s_waitcnt vmcnt(0)" ::: "memory");
    unsigned spins = 0;
    while (!*broken && *flag < epoch) {
      __builtin_amdgcn_s_sleep(1);
      asm volatile("buffer_inv" ::: "memory");
      if (++spins > 2000000u) *broken = 1;
    }
  }
  __syncthreads();
  asm volatile("buffer_inv" ::: "memory");
}

// ---------------------------------------------------------------------
// main persistent kernel, templated for diagnostics.
// MODE 0: full (real output).  1: barriers only.  2: barriers+staging.
// MODE 3: work only (xbar -> __syncthreads; races; writes to ws sink).
// ---------------------------------------------------------------------
template <int MODE>
__launch_bounds__(256, 1)
__global__ void spinn_kernel(const float* __restrict__ bufs,
                             const float* __restrict__ Wtrans, const float* __restrict__ btrans,
                             const float* __restrict__ bredv,
                             float* __restrict__ ws, float* __restrict__ out,
                             int nstep, int nslot, int baroff) {
  extern __shared__ float lds[];
  int* ibuf = (int*)(lds + L_INT);
  int* redl = ibuf + 16;
  int* shl  = ibuf + 32;
  int* sptr = ibuf + 48;
  int* bptr = ibuf + 64;
  volatile int* broken = ibuf + 82;
  int* role_s = ibuf + 90;
  int* trw = (int*)(lds + L_TRW);

  const int tid = threadIdx.x;

  unsigned xcc;
  asm volatile("s_getreg_b32 %0, hwreg(HW_REG_XCC_ID)" : "=s"(xcc));
  xcc &= 7u;
  if (tid == 0) {
    unsigned slot = __hip_atomic_fetch_add((unsigned*)(ws + baroff) + 512 + xcc, 1u,
                                           __ATOMIC_RELAXED, __HIP_MEMORY_SCOPE_AGENT);
    *role_s = (int)slot;
    *broken = 0;
  }
  __syncthreads();
  const int role = *role_s;
  const int group = (int)xcc;
  if (role >= nslot) return;

  const int b0 = group * NB;
  const bool isE = (role < NE);
  const int e  = role;
  const int tb = role - NE;
  const int u0 = (tb >= 0) ? tb*9 : 0;
  const int ucnt = (tb == 6) ? 10 : 9;

  volatile unsigned* slots = (volatile unsigned*)((unsigned*)(ws + baroff) + (size_t)group*64);
  volatile unsigned* flag  = slots + 32;

  float* stack = ws + OFF_STACK;
  float* thbuf = ws + OFF_TH;

  float tc_reg = 0.0f;
  float sink = 0.0f;

  float4 wreg[4][10];
  if constexpr (MODE == 0 || MODE == 3) {
    if (isE) {
      if (tid < 240) {
        const int q = tid >> 4, kq = tid & 15;
        const float* wb = ws + OFF_WEB;
        #pragma unroll
        for (int d = 0; d < 4; ++d)
          #pragma unroll
          for (int i = 0; i < 10; ++i)
            wreg[d][i] = *(const float4*)(wb + (size_t)(e*DOTS_E + 4*q + d)*KE + kq*40 + 4*i);
      }
    } else {
      if (tid < 250) {
        const int q = tid / 25, kq = tid % 25;
        const float* wb = ws + OFF_WTB;
        #pragma unroll
        for (int d = 0; d < 4; ++d)
          #pragma unroll
          for (int i = 0; i < 10; ++i)
            wreg[d][i] = *(const float4*)(wb + (size_t)(tb*DOTS_T + 4*q + d)*KT2 + kq*40 + 4*i);
      }
    }
  }

  if (tid < 16) { sptr[tid] = 0; bptr[tid] = 0; }
  for (int i = tid; i < NSTEP; i += 256)
    trw[i] = ((const int*)(ws + OFF_TPK))[group*NSTEP + i];
  if (isE) {
    for (int i = tid; i < DOTS_E*65; i += 256)
      lds[L_WTR + i] = ws[OFF_WTR + (size_t)e*DOTS_E*65 + i];
    for (int i = tid; i < DOTS_E; i += 256)
      lds[L_BRED + i] = bredv[(i/JPB)*HD + e*JPB + (i%JPB)];
    for (int i = tid; i < 800; i += 256) lds[615*ASTR + i] = 0.0f;
  } else {
    for (int i = tid; i < 720; i += 256) lds[988*ASTR + i] = 0.0f;
  }
  __syncthreads();

  unsigned epoch = 0;
  int tw = 0;

  for (int t = 0; t < nstep; ++t) {
    const int w = trw[tw] & 0xFFFF;          // bit=1 -> reduce
    tw = (tw == NSTEP-1) ? 0 : tw + 1;
    const int nred = __popc(w);
    if (tid < 16) {
      int rank = __popc(w & ((1u << tid) - 1u));
      if ((w >> tid) & 1) redl[rank] = tid; else shl[tid - rank] = tid;
    }
    __syncthreads();

    // ---- P1 staging into LDS ----
    if constexpr (MODE == 0 || MODE == 2 || MODE == 3) {
      if (isE) {
        int r = tid >> 4, lane = tid & 15;
        if (r < nred) {
          int b = redl[r];
          int sp = sptr[b];
          const float* s2p = stack + ((size_t)((b0+b)*SQ + sp-2))*DW;
          const float* s1p = stack + ((size_t)((b0+b)*SQ + sp-1))*DW;
          #pragma unroll 4
          for (int i = 0; i < 10; ++i) {
            int ch = lane + 16*i;
            if (ch < 150) {
              int sec = ch / 75, kc = ch % 75;
              int dim = kc*4;
              const float* src = (sec == 0) ? s2p : s1p;
              float4 v = *(const float4*)(src + dim);
              int kbase = sec*300 + dim;
              int row0 = (kbase/40)*41 + (kbase%40);
              lds[(row0+0)*ASTR + r] = v.x;
              lds[(row0+1)*ASTR + r] = v.y;
              lds[(row0+2)*ASTR + r] = v.z;
              lds[(row0+3)*ASTR + r] = v.w;
            }
          }
        }
      } else {
        {
          int b = tid >> 4, lane = tid & 15;
          int bp = bptr[b]; if (bp > SQ-1) bp = SQ-1;
          int sp = sptr[b];
          const float* bsrc = bufs + ((size_t)((b0+b)*SQ + bp))*DW;
          const float* s1p = (sp >= 1) ? stack + ((size_t)((b0+b)*SQ + sp-1))*DW : nullptr;
          const float* s2p = (sp >= 2) ? stack + ((size_t)((b0+b)*SQ + sp-2))*DW : nullptr;
          #pragma unroll 4
          for (int i = 0; i < 15; ++i) {
            int ch = lane + 16*i;
            if (ch < 225) {
              int sec = ch / 75, kc = ch % 75;
              int dim = kc*4;
              const float* src = (sec == 0) ? bsrc : ((sec == 1) ? s1p : s2p);
              float4 v = make_float4(0.f, 0.f, 0.f, 0.f);
              if (src) v = *(const float4*)(src + dim);
              int kbase = sec*300 + dim;
              int row0 = (kbase/40)*41 + (kbase%40);
              lds[(row0+0)*ASTR + b] = v.x;
              lds[(row0+1)*ASTR + b] = v.y;
              lds[(row0+2)*ASTR + b] = v.z;
              lds[(row0+3)*ASTR + b] = v.w;
            }
          }
        }
        {
          int pm = (t - 1) & 1;
          int b = tid >> 4, uc = tid & 15;
          float4 v = *(const float4*)(thbuf + ((size_t)pm*HB + (b0+b))*TK + uc*4);
          float vv[4] = {v.x, v.y, v.z, v.w};
          #pragma unroll
          for (int l = 0; l < 4; ++l) {
            int k = 900 + uc*4 + l;
            int row = (k/40)*41 + (k%40);
            lds[row*ASTR + b] = vv[l];
          }
        }
      }
    }
    __syncthreads();
    if constexpr (MODE == 2) sink += lds[(t + tid) & 8191];   // DCE guard

    // ---- P1 compute ----
    if constexpr (MODE == 0 || MODE == 3) {
      if (isE) {
        const int nchunk = (nred + 3) >> 2;
        if (nchunk > 0) {
          if (tid < 240) {
            const int q = tid >> 4, kq = tid & 15;
            const float* ab = lds + kq*SLP;
            float* dmp = lds + L_DUMP;
            #pragma unroll 1
            for (int c = 0; c < nchunk; ++c) {
              float acc[4][4];
              #pragma unroll
              for (int d = 0; d < 4; ++d)
                #pragma unroll
                for (int s = 0; s < 4; ++s) acc[d][s] = 0.0f;
              #pragma unroll
              for (int i = 0; i < 10; ++i) {
                #pragma unroll
                for (int kk = 0; kk < 4; ++kk) {
                  float4 a = *(const float4*)(ab + (4*i + kk)*ASTR + 4*c);
                  #pragma unroll
                  for (int d = 0; d < 4; ++d) {
                    float wv = (kk == 0) ? wreg[d][i].x : (kk == 1) ? wreg[d][i].y
                             : (kk == 2) ? wreg[d][i].z : wreg[d][i].w;
                    acc[d][0] = fmaf(wv, a.x, acc[d][0]);
                    acc[d][1] = fmaf(wv, a.y, acc[d][1]);
                    acc[d][2] = fmaf(wv, a.z, acc[d][2]);
                    acc[d][3] = fmaf(wv, a.w, acc[d][3]);
                  }
                }
              }
              #pragma unroll
              for (int d = 0; d < 4; ++d)
                #pragma unroll
                for (int s = 0; s < 4; ++s)
                  acc[d][s] += __shfl_xor(acc[d][s], 8, 64);
              if (kq < 8) {
                #pragma unroll
                for (int d = 0; d < 4; ++d)
                  *(float4*)(dmp + kq*EDP + (4*q + d)*16 + 4*c) =
                      make_float4(acc[d][0], acc[d][1], acc[d][2], acc[d][3]);
              }
            }
          }
          __syncthreads();
          for (int task = tid; task < DOTS_E*16; task += 256) {
            int dot = task >> 4, s = task & 15;
            float sum = 0.0f;
            #pragma unroll
            for (int kq = 0; kq < 8; ++kq)
              sum += lds[L_DUMP + kq*EDP + dot*16 + s];
            lds[L_DUMP + dot*16 + s] = sum;
          }
        }
      } else {
        if (tid < 250) {
          const int q = tid / 25, kq = tid % 25;
          const float* ab = lds + kq*SLP;
          float* dmp = lds + L_DUMP + kq*TDP;
          #pragma unroll 1
          for (int c = 0; c < 4; ++c) {
            float acc[4][4];
            #pragma unroll
            for (int d = 0; d < 4; ++d)
              #pragma unroll
              for (int s = 0; s < 4; ++s) acc[d][s] = 0.0f;
            #pragma unroll
            for (int i = 0; i < 10; ++i) {
              #pragma unroll
              for (int kk = 0; kk < 4; ++kk) {
                float4 a = *(const float4*)(ab + (4*i + kk)*ASTR + 4*c);
                #pragma unroll
                for (int d = 0; d < 4; ++d) {
                  float wv = (kk == 0) ? wreg[d][i].x : (kk == 1) ? wreg[d][i].y
                           : (kk == 2) ? wreg[d][i].z : wreg[d][i].w;
                  acc[d][0] = fmaf(wv, a.x, acc[d][0]);
                  acc[d][1] = fmaf(wv, a.y, acc[d][1]);
                  acc[d][2] = fmaf(wv, a.z, acc[d][2]);
                  acc[d][3] = fmaf(wv, a.w, acc[d][3]);
                }
              }
            }
            #pragma unroll
            for (int d = 0; d < 4; ++d)
              *(float4*)(dmp + (4*q + d)*16 + 4*c) =
                  make_float4(acc[d][0], acc[d][1], acc[d][2], acc[d][3]);
          }
        }
        __syncthreads();
        for (int task = tid; task < DOTS_T*16; task += 256) {
          int dot = task >> 4, s = task & 15;
          float sum = 0.0f;
          #pragma unroll
          for (int kq = 0; kq < 25; ++kq)
            sum += lds[L_DUMP + kq*TDP + dot*16 + s];
          lds[L_DUMP + dot*16 + s] = sum;
        }
        __syncthreads();
        if (tid < 160) {
          int uu = tid >> 4, b = tid & 15;
          if (uu < ucnt) {
            float gi = lds[L_DUMP + (0*UPB + uu)*16 + b];
            float gf = lds[L_DUMP + (1*UPB + uu)*16 + b];
            float gg = lds[L_DUMP + (2*UPB + uu)*16 + b];
            float go = lds[L_DUMP + (3*UPB + uu)*16 + b];
            tc_reg = sigf(gf)*tc_reg + sigf(gi)*tanhf(gg);
            float th = sigf(go)*tanhf(tc_reg);
            thbuf[((size_t)(t & 1)*HB + (b0 + b))*TK + (u0 + uu)] = th;
          }
        }
      }
    }

    ++epoch;
    if constexpr (MODE == 3) __syncthreads();
    else xbar(role, epoch, nslot, slots, flag, broken);   // th(t) visible

    // ---- P2 ----
    if constexpr (MODE == 0 || MODE == 3) {
      if (isE) {
        int p = t & 1;
        {
          int r = tid >> 4, lane = tid & 15;
          if (r < nred) {
            const float* thp = thbuf + ((size_t)p*HB + (b0 + redl[r]))*TK;
            #pragma unroll
            for (int i = 0; i < 4; ++i) {
              int k = lane + 16*i;
              lds[L_THL + r*65 + k] = thp[k];
            }
          }
        }
        __syncthreads();
        if (tid < 192) {
          int rr = tid / JPB, jj = tid % JPB;
          int j = e*JPB + jj;
          if (rr < nred) {
            int b = redl[rr];
            int sp = sptr[b];
            float* s2base = stack + ((size_t)((b0+b)*SQ + (sp-2)))*DW;
            const float* s1base = stack + ((size_t)((b0+b)*SQ + (sp-1)))*DW;
            float s2c = s2base[HD + j];
            float s1c = s1base[HD + j];
            float a0 = lds[L_DUMP + (0*JPB + jj)*16 + rr] + lds[L_BRED + 0*JPB + jj];
            float a1 = lds[L_DUMP + (1*JPB + jj)*16 + rr] + lds[L_BRED + 1*JPB + jj];
            float a2 = lds[L_DUMP + (2*JPB + jj)*16 + rr] + lds[L_BRED + 2*JPB + jj];
            float a3 = lds[L_DUMP + (3*JPB + jj)*16 + rr] + lds[L_BRED + 3*JPB + jj];
            float a4 = lds[L_DUMP + (4*JPB + jj)*16 + rr] + lds[L_BRED + 4*JPB + jj];
            #pragma unroll 8
            for (int k = 0; k < 64; ++k) {
              float tv = lds[L_THL + rr*65 + k];
              a0 = fmaf(tv, lds[L_WTR + (0*JPB + jj)*65 + k], a0);
              a1 = fmaf(tv, lds[L_WTR + (1*JPB + jj)*65 + k], a1);
              a2 = fmaf(tv, lds[L_WTR + (2*JPB + jj)*65 + k], a2);
              a3 = fmaf(tv, lds[L_WTR + (3*JPB + jj)*65 + k], a3);
              a4 = fmaf(tv, lds[L_WTR + (4*JPB + jj)*65 + k], a4);
            }
            float rc = sigf(a1)*s2c + sigf(a2)*s1c + sigf(a0)*tanhf(a4);
            float rh = sigf(a3)*tanhf(rc);
            s2base[j] = rh;
            s2base[HD + j] = rc;
          } else {
            int b = shl[rr - nred];
            int sp = sptr[b], bp = bptr[b];
            if (bp > SQ-1) bp = SQ-1;
            const float* src = bufs + ((size_t)((b0+b)*SQ + bp))*DW;
            float* dst = stack + ((size_t)((b0+b)*SQ + sp))*DW;
            dst[j] = src[j];
            dst[HD + j] = src[HD + j];
          }
        }
      } else if (role == NE) {
        if (tid < 32) {
          int b = tid >> 1, c = tid & 1;
          const float* th = thbuf + ((size_t)(t & 1)*HB + (b0 + b))*TK;
          float s = btrans[c];
          #pragma unroll 8
          for (int u = 0; u < TK; ++u) s = fmaf(th[u], Wtrans[u*2 + c], s);
          if (t < NSTEP) out[(size_t)(b0 + b)*OUTW + HD + 2*t + c] = s;
        }
      }
    }

    __syncthreads();
    if (tid < 16) {
      if (!((w >> tid) & 1)) { sptr[tid] += 1; bptr[tid] += 1; }
      else                   { sptr[tid] -= 1; }
      if constexpr (MODE != 0) {   // diag runs wrap the transition seq
        if (sptr[tid] < 0) sptr[tid] = 0;
        if (sptr[tid] > 250) sptr[tid] = 250;
        if (bptr[tid] > SQ-1) bptr[tid] = SQ-1;
      }
    }

    ++epoch;
    if constexpr (MODE == 3) __syncthreads();
    else xbar(role, epoch, nslot, slots, flag, broken);   // stack(t) visible
  }

  if constexpr (MODE == 0 || MODE == 3) {
    if (isE && tid < 192) {
      int b = tid / JPB, jj = tid % JPB;
      int j = e*JPB + jj;
      int sp = sptr[b] - 1; if (sp < 0) sp = 0;
      out[(size_t)(b0 + b)*OUTW + j] =
          stack[((size_t)((b0 + b)*SQ + sp))*DW + j];
    }
  }
  if constexpr (MODE == 2) {
    if (sink == 1.2345e-30f) out[0] = sink;   // keep staging live
  }
}

// ---------------------------------------------------------------------
extern "C" void kernel_launch(void* const* d_in, const int* in_sizes, int n_in,
                              void* d_out, int out_size, void* d_ws, size_t ws_size,
                              hipStream_t stream) {
  const float* bufs   = (const float*)d_in[0];
  const int*   trans  = (const int*)  d_in[1];
  const float* Wbuf   = (const float*)d_in[2];
  const float* Ws1    = (const float*)d_in[3];
  const float* Ws2    = (const float*)d_in[4];
  const float* Wih    = (const float*)d_in[5];
  const float* Whh    = (const float*)d_in[6];
  const float* Wtrans = (const float*)d_in[7];
  const float* btrans = (const float*)d_in[8];
  const float* Wl     = (const float*)d_in[9];
  const float* Wr     = (const float*)d_in[10];
  const float* Wtrk   = (const float*)d_in[11];
  const float* bredv  = (const float*)d_in[12];
  float* ws  = (float*)d_ws;
  float* out = (float*)d_out;

  if (ws_size < (size_t)WS_FLOATS * sizeof(float)) return;

  {
    int total = N_WCT + N_TH + N_BAR + N_BARD + 8*NSTEP;
    prep_a<<<(total + 255) / 256, 256, 0, stream>>>(Wbuf, Ws1, Ws2, trans, ws);
  }
  {
    int total = N_WEB + N_WTB + N_WTR;
    prep_b<<<(total + 255) / 256, 256, 0, stream>>>(Wih, Whh, Wl, Wr, Wtrk, ws);
  }
  size_t ldsb = LDS_FLOATS * sizeof(float);
  (void)hipFuncSetAttribute((const void*)spinn_kernel<0>, hipFuncAttributeMaxDynamicSharedMemorySize, 160000);
  (void)hipFuncSetAttribute((const void*)spinn_kernel<1>, hipFuncAttributeMaxDynamicSharedMemorySize, 160000);
  (void)hipFuncSetAttribute((const void*)spinn_kernel<2>, hipFuncAttributeMaxDynamicSharedMemorySize, 160000);
  (void)hipFuncSetAttribute((const void*)spinn_kernel<3>, hipFuncAttributeMaxDynamicSharedMemorySize, 160000);

  // real kernel (correct output)
  spinn_kernel<0><<<256, 256, ldsb, stream>>>(bufs, Wtrans, btrans, bredv, ws, out,
                                              NSTEP, 32, OFF_BAR);
  // diagnostics (write only to ws scratch; sink = stack region)
  float* sinkp = ws + OFF_STACK;
  spinn_kernel<1><<<256, 256, ldsb, stream>>>(bufs, Wtrans, btrans, bredv, ws, sinkp,
                                              4*NSTEP, 32, OFF_BARD);          // barriers only
  spinn_kernel<2><<<256, 256, ldsb, stream>>>(bufs, Wtrans, btrans, bredv, ws, sinkp,
                                              4*NSTEP, 32, OFF_BARD + 520);    // +staging
  spinn_kernel<3><<<256, 256, ldsb, stream>>>(bufs, Wtrans, btrans, bredv, ws, sinkp,
                                              8*NSTEP, 32, OFF_BARD + 1040);   // work only
}

// Round 9
// 19366.412 us; speedup vs baseline: 8.9138x; 8.9138x over previous
//
#include <hip/hip_runtime.h>

// =====================================================================
// SPINN-style stack LSTM, MI355X.
// 8 groups (one per XCD via HW_REG_XCC_ID) x 16 batch; 32 blocks/group.
// R9: R8 diagnostics proved barrier-pair <0.5us and staging ~free; the
// 26us/step was the WORK at 1 wave/SIMD (OccupancyPercent 12 -> zero
// latency hiding on the ds_read->fma chains). Fix: 1024-thread blocks
// (16 waves/CU = 4/SIMD), work split 4x finer: each thread owns 1 dot x
// 40 k = 40 wreg fp32 (E: 960 thr, T: 1000 thr) -> VGPR<=128 via
// __launch_bounds__(1024,4), no spill. P2 k-split 4-way (768 thr +
// shfl_xor reduce). Barrier/LDS/math identical to R7 (absmax 9.8e-4).
// =====================================================================

#define NSTEP 511
#define HB 128
#define SQ 256
#define HD 300
#define DW 600
#define TK 64

#define NB 16
#define NE 25           // E blocks per group
#define JPB 12          // j dims per E block
#define DOTS_E 60       // 5 gates * 12 j
#define KE 640          // padded 600
#define UPB 10
#define DOTS_T 40       // 4 gates * 10 units
#define KT2 1000        // padded 964 (900 fused + 64 hh + 36 zero)
#define ASTR 20         // act row stride (floats), 16 slots + pad
#define SLP 820         // act slice pitch = 41 rows * ASTR
#define OUTW 1322

// ---- workspace layout (floats) ----
#define N_WEB 960000            // 25*60*640   E weight slices fp32
#define N_WTB 280000            // 7*40*1000   T fused weight slices fp32
#define N_WTR 97500             // 25*60*65    W_track slices
#define N_TH  16384             // 2*128*64    th double buffer
#define N_STACK 19660800        // 128*256*600
#define N_BAR 1024
#define N_TPK 4096
#define N_WCT 230400            // WcatT (prep only, overlaps stack)

#define OFF_WEB 0
#define OFF_WTB 960000
#define OFF_WTR 1240000
#define OFF_TH  1337504
#define OFF_STACK 1353888
#define OFF_BAR 21014688
#define OFF_TPK 21015712
#define WS_FLOATS 21019808
#define OFF_WCT OFF_STACK

// ---- LDS layout (floats) ----
#define L_ACT 0                 // 25 slices * SLP = 20500
#define L_DUMP 20500            // E: 8*EDP=7712 ; T: 25*TDP=16100
#define EDP 964                 // E dump kq pitch (60*16 + 4 skew)
#define TDP 644                 // T dump kq pitch (40*16 + 4 skew)
#define L_WTR 28212             // (E only) 60*65 = 3900
#define L_THL 32112             // 16*65 = 1040
#define L_BRED 33152            // 60(+pad)
#define L_TRW 36600             // 511 ints (+1)
#define L_INT 37112             // 96 ints
#define LDS_FLOATS 37208        // 148832 B (>80KB => 1 block/CU)

__device__ __forceinline__ float sigf(float x) { return 1.0f / (1.0f + __expf(-x)); }

// ---------------------------------------------------------------------
// prep_a: WcatT[256][900], zero th/barrier, pack transitions.
// ---------------------------------------------------------------------
__global__ void prep_a(const float* __restrict__ Wbuf, const float* __restrict__ Ws1,
                       const float* __restrict__ Ws2, const int* __restrict__ trans,
                       float* __restrict__ ws) {
  int idx = blockIdx.x * 256 + threadIdx.x;
  if (idx < N_WCT) {
    int k = idx % 900;
    int m = idx / 900;
    float v = (k < 300) ? Wbuf[k*256 + m]
            : (k < 600) ? Ws1[(k-300)*256 + m]
                        : Ws2[(k-600)*256 + m];
    ws[OFF_WCT + idx] = v;
    return;
  }
  idx -= N_WCT;
  if (idx < N_TH) { ws[OFF_TH + idx] = 0.0f; return; }
  idx -= N_TH;
  if (idx < N_BAR) { ws[OFF_BAR + idx] = 0.0f; return; }
  idx -= N_BAR;
  if (idx < 8*NSTEP) {
    int g = idx / NSTEP, t = idx % NSTEP;
    int w = 0;
    #pragma unroll
    for (int b = 0; b < 16; ++b)
      w |= (trans[(size_t)(g*16 + b)*NSTEP + t] & 1) << b;
    ((int*)(ws + OFF_TPK))[g*NSTEP + t] = w;
  }
}

// ---------------------------------------------------------------------
// prep_b: fp32 transposed weight slices; tracker input projection fused
// with W_ih: WT[col][k<900] = sum_m Wcat[k][m] * W_ih[col][m]  (exact).
// ---------------------------------------------------------------------
__global__ void prep_b(const float* __restrict__ Wih, const float* __restrict__ Whh,
                       const float* __restrict__ Wl, const float* __restrict__ Wr,
                       const float* __restrict__ Wtrk, float* __restrict__ ws) {
  int idx = blockIdx.x * 256 + threadIdx.x;
  if (idx < N_WEB) {
    int k = idx % KE; int rest = idx / KE;
    int dot = rest % DOTS_E; int e = rest / DOTS_E;
    int g = dot / JPB, jj = dot % JPB;
    int col = g*HD + e*JPB + jj;
    float v = 0.0f;
    if (k < 300)      v = Wl[k*1500 + col];
    else if (k < 600) v = Wr[(k-300)*1500 + col];
    ws[OFF_WEB + idx] = v;
    return;
  }
  idx -= N_WEB;
  if (idx < N_WTB) {
    int k = idx % KT2; int rest = idx / KT2;
    int dot = rest % DOTS_T; int tb = rest / DOTS_T;
    int g = dot / UPB, uu = dot % UPB;
    int ucnt = (tb == 6) ? 10 : 9;
    float v = 0.0f;
    if (uu < ucnt) {
      int col = g*TK + tb*9 + uu;
      if (k < 900) {
        const float* wct = ws + OFF_WCT;
        const float* wi  = Wih + col*256;
        float s = 0.0f;
        #pragma unroll 4
        for (int m = 0; m < 256; ++m) s = fmaf(wct[m*900 + k], wi[m], s);
        v = s;
      } else if (k < 964) {
        v = Whh[col*TK + (k - 900)];
      }
    }
    ws[OFF_WTB + idx] = v;
    return;
  }
  idx -= N_WTB;
  if (idx < N_WTR) {
    int k = idx % 65; int rest = idx / 65;
    int dot = rest % DOTS_E; int e = rest / DOTS_E;
    int g = dot / JPB, jj = dot % JPB;
    ws[OFF_WTR + idx] = (k < 64) ? Wtrk[k*1500 + (g*HD + e*JPB + jj)] : 0.0f;
  }
}

// ---------------------------------------------------------------------
// fence-free XCD-local barrier (R2/R7 design; R8 D1 measured <0.5us/pair).
// ---------------------------------------------------------------------
__device__ __forceinline__ void xbar(int role, unsigned epoch,
                                     volatile unsigned* slots, volatile unsigned* flag,
                                     volatile int* broken) {
  __syncthreads();                      // drains vmcnt on every wave
  if (role == 0) {
    if (threadIdx.x < 64) {
      int lane = threadIdx.x;
      unsigned spins = 0;
      for (;;) {
        if (*broken) break;
        unsigned v = (lane >= 1 && lane < 32) ? slots[lane] : epoch;
        if (__all(v >= epoch)) break;
        __builtin_amdgcn_s_sleep(1);
        asm volatile("buffer_inv" ::: "memory");
        if (++spins > 2000000u) { if (lane == 0) *broken = 1; break; }
      }
      if (lane == 0) {
        *flag = epoch;
        asm volatile("s_waitcnt vmcnt(0)" ::: "memory");
      }
    }
  } else if (threadIdx.x == 0) {
    slots[role] = epoch;
    asm volatile("s_waitcnt vmcnt(0)" ::: "memory");
    unsigned spins = 0;
    while (!*broken && *flag < epoch) {
      __builtin_amdgcn_s_sleep(1);
      asm volatile("buffer_inv" ::: "memory");
      if (++spins > 2000000u) *broken = 1;
    }
  }
  __syncthreads();
  asm volatile("buffer_inv" ::: "memory");
}

// ---------------------------------------------------------------------
// main persistent kernel: 256 blocks x 1024 threads, 1 block/CU (LDS),
// 16 waves/CU = 4 waves/SIMD.
// ---------------------------------------------------------------------
__launch_bounds__(1024, 4)
__global__ void spinn_kernel(const float* __restrict__ bufs,
                             const float* __restrict__ Wtrans, const float* __restrict__ btrans,
                             const float* __restrict__ bredv,
                             float* __restrict__ ws, float* __restrict__ out) {
  extern __shared__ float lds[];
  int* ibuf = (int*)(lds + L_INT);
  int* redl = ibuf + 16;
  int* shl  = ibuf + 32;
  int* sptr = ibuf + 48;
  int* bptr = ibuf + 64;
  volatile int* broken = ibuf + 82;
  int* role_s = ibuf + 90;
  int* trw = (int*)(lds + L_TRW);

  const int tid = threadIdx.x;

  // ---- runtime XCD-local grouping (one-time) ----
  unsigned xcc;
  asm volatile("s_getreg_b32 %0, hwreg(HW_REG_XCC_ID)" : "=s"(xcc));
  xcc &= 7u;
  if (tid == 0) {
    unsigned slot = __hip_atomic_fetch_add((unsigned*)(ws + OFF_BAR) + 512 + xcc, 1u,
                                           __ATOMIC_RELAXED, __HIP_MEMORY_SCOPE_AGENT);
    *role_s = (int)slot;
    *broken = 0;
  }
  __syncthreads();
  const int role = *role_s;
  const int group = (int)xcc;
  if (role >= 32) return;

  const int b0 = group * NB;
  const bool isE = (role < NE);
  const int e  = role;
  const int tb = role - NE;
  const int u0 = (tb >= 0) ? tb*9 : 0;
  const int ucnt = (tb == 6) ? 10 : 9;

  volatile unsigned* slots = (volatile unsigned*)((unsigned*)(ws + OFF_BAR) + (size_t)group*64);
  volatile unsigned* flag  = slots + 32;

  float* stack = ws + OFF_STACK;
  float* thbuf = ws + OFF_TH;

  float tc_reg = 0.0f;

  // ---- preload this thread's fp32 weight slice: 1 dot x 40 k = 40 VGPRs ----
  float4 wreg[10];
  if (isE) {
    if (tid < 960) {
      const int q = tid >> 4, kq = tid & 15;       // q = dot 0..59
      const float* wb = ws + OFF_WEB + (size_t)(e*DOTS_E + q)*KE + kq*40;
      #pragma unroll
      for (int i = 0; i < 10; ++i) wreg[i] = *(const float4*)(wb + 4*i);
    }
  } else {
    if (tid < 1000) {
      const int q = tid / 25, kq = tid % 25;       // q = dot 0..39
      const float* wb = ws + OFF_WTB + (size_t)(tb*DOTS_T + q)*KT2 + kq*40;
      #pragma unroll
      for (int i = 0; i < 10; ++i) wreg[i] = *(const float4*)(wb + 4*i);
    }
  }

  // ---- one-time init ----
  if (tid < 16) { sptr[tid] = 0; bptr[tid] = 0; }
  for (int i = tid; i < NSTEP; i += 1024)
    trw[i] = ((const int*)(ws + OFF_TPK))[group*NSTEP + i];
  if (isE) {
    for (int i = tid; i < DOTS_E*65; i += 1024)
      lds[L_WTR + i] = ws[OFF_WTR + (size_t)e*DOTS_E*65 + i];
    for (int i = tid; i < DOTS_E; i += 1024)
      lds[L_BRED + i] = bredv[(i/JPB)*HD + e*JPB + (i%JPB)];
    for (int i = tid; i < 800; i += 1024) lds[615*ASTR + i] = 0.0f;   // k 600..639
  } else {
    for (int i = tid; i < 720; i += 1024) lds[988*ASTR + i] = 0.0f;   // k 964..999
  }
  __syncthreads();

  unsigned epoch = 0;

  for (int t = 0; t < NSTEP; ++t) {
    // ---- prologue: transition word + compact lists ----
    const int w = trw[t] & 0xFFFF;          // bit=1 -> reduce
    const int nred = __popc(w);
    if (tid < 16) {
      int rank = __popc(w & ((1u << tid) - 1u));
      if ((w >> tid) & 1) redl[rank] = tid; else shl[tid - rank] = tid;
    }
    __syncthreads();

    // ---- P1 staging into LDS (row(k) = (k/40)*41 + k%40) ----
    if (isE) {
      int r = tid >> 6, lane = tid & 63;
      if (r < nred) {
        int b = redl[r];
        int sp = sptr[b];
        const float* s2p = stack + ((size_t)((b0+b)*SQ + sp-2))*DW;
        const float* s1p = stack + ((size_t)((b0+b)*SQ + sp-1))*DW;
        #pragma unroll
        for (int i = 0; i < 3; ++i) {
          int ch = lane + 64*i;
          if (ch < 150) {
            int sec = ch / 75, kc = ch % 75;
            int dim = kc*4;
            const float* src = (sec == 0) ? s2p : s1p;
            float4 v = *(const float4*)(src + dim);
            int kbase = sec*300 + dim;
            int row0 = (kbase/40)*41 + (kbase%40);
            lds[(row0+0)*ASTR + r] = v.x;
            lds[(row0+1)*ASTR + r] = v.y;
            lds[(row0+2)*ASTR + r] = v.z;
            lds[(row0+3)*ASTR + r] = v.w;
          }
        }
      }
    } else {
      {
        int b = tid >> 6, lane = tid & 63;
        int bp = bptr[b]; if (bp > SQ-1) bp = SQ-1;
        int sp = sptr[b];
        const float* bsrc = bufs + ((size_t)((b0+b)*SQ + bp))*DW;
        const float* s1p = (sp >= 1) ? stack + ((size_t)((b0+b)*SQ + sp-1))*DW : nullptr;
        const float* s2p = (sp >= 2) ? stack + ((size_t)((b0+b)*SQ + sp-2))*DW : nullptr;
        #pragma unroll
        for (int i = 0; i < 4; ++i) {
          int ch = lane + 64*i;
          if (ch < 225) {
            int sec = ch / 75, kc = ch % 75;
            int dim = kc*4;
            const float* src = (sec == 0) ? bsrc : ((sec == 1) ? s1p : s2p);
            float4 v = make_float4(0.f, 0.f, 0.f, 0.f);
            if (src) v = *(const float4*)(src + dim);
            int kbase = sec*300 + dim;
            int row0 = (kbase/40)*41 + (kbase%40);
            lds[(row0+0)*ASTR + b] = v.x;
            lds[(row0+1)*ASTR + b] = v.y;
            lds[(row0+2)*ASTR + b] = v.z;
            lds[(row0+3)*ASTR + b] = v.w;
          }
        }
      }
      if (tid < 256) {   // th(t-1) -> k 900..963 ; t=0 reads zeroed parity-1
        int pm = (t - 1) & 1;
        int b = tid >> 4, uc = tid & 15;
        float4 v = *(const float4*)(thbuf + ((size_t)pm*HB + (b0+b))*TK + uc*4);
        float vv[4] = {v.x, v.y, v.z, v.w};
        #pragma unroll
        for (int l = 0; l < 4; ++l) {
          int k = 900 + uc*4 + l;
          int row = (k/40)*41 + (k%40);
          lds[row*ASTR + b] = vv[l];
        }
      }
    }
    __syncthreads();

    // ---- P1 compute (1 dot/thread, weights in VGPRs, acc[4]/chunk) ----
    if (isE) {
      const int nchunk = (nred + 3) >> 2;
      if (nchunk > 0) {
        if (tid < 960) {
          const int q = tid >> 4, kq = tid & 15;
          const float* ab = lds + kq*SLP;
          float* dmp = lds + L_DUMP;
          #pragma unroll 1
          for (int c = 0; c < nchunk; ++c) {
            float a0 = 0.f, a1 = 0.f, a2 = 0.f, a3 = 0.f;
            #pragma unroll
            for (int i = 0; i < 10; ++i) {
              #pragma unroll
              for (int kk = 0; kk < 4; ++kk) {
                float4 a = *(const float4*)(ab + (4*i + kk)*ASTR + 4*c);
                float wv = (kk == 0) ? wreg[i].x : (kk == 1) ? wreg[i].y
                         : (kk == 2) ? wreg[i].z : wreg[i].w;
                a0 = fmaf(wv, a.x, a0);
                a1 = fmaf(wv, a.y, a1);
                a2 = fmaf(wv, a.z, a2);
                a3 = fmaf(wv, a.w, a3);
              }
            }
            a0 += __shfl_xor(a0, 8, 64);
            a1 += __shfl_xor(a1, 8, 64);
            a2 += __shfl_xor(a2, 8, 64);
            a3 += __shfl_xor(a3, 8, 64);
            if (kq < 8)
              *(float4*)(dmp + kq*EDP + q*16 + 4*c) = make_float4(a0, a1, a2, a3);
          }
        }
        __syncthreads();
        for (int task = tid; task < DOTS_E*16; task += 1024) {
          int dot = task >> 4, s = task & 15;
          float sum = 0.0f;
          #pragma unroll
          for (int kq = 0; kq < 8; ++kq)
            sum += lds[L_DUMP + kq*EDP + dot*16 + s];
          lds[L_DUMP + dot*16 + s] = sum;   // compact a_red
        }
      }
    } else {
      if (tid < 1000) {
        const int q = tid / 25, kq = tid % 25;
        const float* ab = lds + kq*SLP;
        float* dmp = lds + L_DUMP + kq*TDP;
        #pragma unroll 1
        for (int c = 0; c < 4; ++c) {
          float a0 = 0.f, a1 = 0.f, a2 = 0.f, a3 = 0.f;
          #pragma unroll
          for (int i = 0; i < 10; ++i) {
            #pragma unroll
            for (int kk = 0; kk < 4; ++kk) {
              float4 a = *(const float4*)(ab + (4*i + kk)*ASTR + 4*c);
              float wv = (kk == 0) ? wreg[i].x : (kk == 1) ? wreg[i].y
                       : (kk == 2) ? wreg[i].z : wreg[i].w;
              a0 = fmaf(wv, a.x, a0);
              a1 = fmaf(wv, a.y, a1);
              a2 = fmaf(wv, a.z, a2);
              a3 = fmaf(wv, a.w, a3);
            }
          }
          *(float4*)(dmp + q*16 + 4*c) = make_float4(a0, a1, a2, a3);
        }
      }
      __syncthreads();
      for (int task = tid; task < DOTS_T*16; task += 1024) {
        int dot = task >> 4, s = task & 15;
        float sum = 0.0f;
        #pragma unroll
        for (int kq = 0; kq < 25; ++kq)
          sum += lds[L_DUMP + kq*TDP + dot*16 + s];
        lds[L_DUMP + dot*16 + s] = sum;     // compact gates
      }
      __syncthreads();
      if (tid < 160) {
        int uu = tid >> 4, b = tid & 15;
        if (uu < ucnt) {
          float gi = lds[L_DUMP + (0*UPB + uu)*16 + b];
          float gf = lds[L_DUMP + (1*UPB + uu)*16 + b];
          float gg = lds[L_DUMP + (2*UPB + uu)*16 + b];
          float go = lds[L_DUMP + (3*UPB + uu)*16 + b];
          tc_reg = sigf(gf)*tc_reg + sigf(gi)*tanhf(gg);
          float th = sigf(go)*tanhf(tc_reg);
          thbuf[((size_t)(t & 1)*HB + (b0 + b))*TK + (u0 + uu)] = th;
        }
      }
    }

    ++epoch;
    xbar(role, epoch, slots, flag, broken);   // th(t) visible

    // ---- P2 (k-split 4-way: thread = (rr, jj, ks)) ----
    if (isE) {
      int p = t & 1;
      if (tid < 256) {
        int r = tid >> 4, lane = tid & 15;
        if (r < nred) {
          const float* thp = thbuf + ((size_t)p*HB + (b0 + redl[r]))*TK;
          #pragma unroll
          for (int i = 0; i < 4; ++i) {
            int k = lane + 16*i;
            lds[L_THL + r*65 + k] = thp[k];
          }
        }
      }
      __syncthreads();
      if (tid < 768) {
        int rr = tid / 48, rem = tid % 48;
        int jj = rem >> 2, ks = rem & 3;
        int j = e*JPB + jj;
        if (rr < nred) {
          int b = redl[rr];
          int sp = sptr[b];
          float* s2base = stack + ((size_t)((b0+b)*SQ + (sp-2)))*DW;
          const float* s1base = stack + ((size_t)((b0+b)*SQ + (sp-1)))*DW;
          float a0 = 0.f, a1 = 0.f, a2 = 0.f, a3 = 0.f, a4 = 0.f;
          const float* thl = lds + L_THL + rr*65 + ks*16;
          const float* w0 = lds + L_WTR + (0*JPB + jj)*65 + ks*16;
          const float* w1 = lds + L_WTR + (1*JPB + jj)*65 + ks*16;
          const float* w2 = lds + L_WTR + (2*JPB + jj)*65 + ks*16;
          const float* w3 = lds + L_WTR + (3*JPB + jj)*65 + ks*16;
          const float* w4 = lds + L_WTR + (4*JPB + jj)*65 + ks*16;
          #pragma unroll
          for (int k = 0; k < 16; ++k) {
            float tv = thl[k];
            a0 = fmaf(tv, w0[k], a0);
            a1 = fmaf(tv, w1[k], a1);
            a2 = fmaf(tv, w2[k], a2);
            a3 = fmaf(tv, w3[k], a3);
            a4 = fmaf(tv, w4[k], a4);
          }
          a0 += __shfl_xor(a0, 1, 64); a0 += __shfl_xor(a0, 2, 64);
          a1 += __shfl_xor(a1, 1, 64); a1 += __shfl_xor(a1, 2, 64);
          a2 += __shfl_xor(a2, 1, 64); a2 += __shfl_xor(a2, 2, 64);
          a3 += __shfl_xor(a3, 1, 64); a3 += __shfl_xor(a3, 2, 64);
          a4 += __shfl_xor(a4, 1, 64); a4 += __shfl_xor(a4, 2, 64);
          if (ks == 0) {
            a0 += lds[L_DUMP + (0*JPB + jj)*16 + rr] + lds[L_BRED + 0*JPB + jj];
            a1 += lds[L_DUMP + (1*JPB + jj)*16 + rr] + lds[L_BRED + 1*JPB + jj];
            a2 += lds[L_DUMP + (2*JPB + jj)*16 + rr] + lds[L_BRED + 2*JPB + jj];
            a3 += lds[L_DUMP + (3*JPB + jj)*16 + rr] + lds[L_BRED + 3*JPB + jj];
            a4 += lds[L_DUMP + (4*JPB + jj)*16 + rr] + lds[L_BRED + 4*JPB + jj];
            float s2c = s2base[HD + j];
            float s1c = s1base[HD + j];
            float rc = sigf(a1)*s2c + sigf(a2)*s1c + sigf(a0)*tanhf(a4);
            float rh = sigf(a3)*tanhf(rc);
            s2base[j] = rh;
            s2base[HD + j] = rc;
          }
        } else {   // shift: copy buf top -> stack[sp] (ks 0/1 split h/c)
          int b = shl[rr - nred];
          int sp = sptr[b], bp = bptr[b];
          const float* src = bufs + ((size_t)((b0+b)*SQ + bp))*DW;
          float* dst = stack + ((size_t)((b0+b)*SQ + sp))*DW;
          if (ks == 0) dst[j] = src[j];
          else if (ks == 1) dst[HD + j] = src[HD + j];
        }
      }
    } else if (role == NE) {   // logits
      if (tid < 32) {
        int b = tid >> 1, c = tid & 1;
        const float* th = thbuf + ((size_t)(t & 1)*HB + (b0 + b))*TK;
        float s = btrans[c];
        #pragma unroll 8
        for (int u = 0; u < TK; ++u) s = fmaf(th[u], Wtrans[u*2 + c], s);
        out[(size_t)(b0 + b)*OUTW + HD + 2*t + c] = s;
      }
    }

    __syncthreads();
    if (tid < 16) {
      if (!((w >> tid) & 1)) { sptr[tid] += 1; bptr[tid] += 1; }
      else                   { sptr[tid] -= 1; }
    }

    ++epoch;
    xbar(role, epoch, slots, flag, broken);   // stack(t) visible
  }

  // ---- final sentence encoding ----
  if (isE && tid < 192) {
    int b = tid / JPB, jj = tid % JPB;
    int j = e*JPB + jj;
    int sp = sptr[b] - 1; if (sp < 0) sp = 0;
    out[(size_t)(b0 + b)*OUTW + j] =
        stack[((size_t)((b0 + b)*SQ + sp))*DW + j];
  }
}

// ---------------------------------------------------------------------
extern "C" void kernel_launch(void* const* d_in, const int* in_sizes, int n_in,
                              void* d_out, int out_size, void* d_ws, size_t ws_size,
                              hipStream_t stream) {
  const float* bufs   = (const float*)d_in[0];
  const int*   trans  = (const int*)  d_in[1];
  const float* Wbuf   = (const float*)d_in[2];
  const float* Ws1    = (const float*)d_in[3];
  const float* Ws2    = (const float*)d_in[4];
  const float* Wih    = (const float*)d_in[5];
  const float* Whh    = (const float*)d_in[6];
  const float* Wtrans = (const float*)d_in[7];
  const float* btrans = (const float*)d_in[8];
  const float* Wl     = (const float*)d_in[9];
  const float* Wr     = (const float*)d_in[10];
  const float* Wtrk   = (const float*)d_in[11];
  const float* bredv  = (const float*)d_in[12];
  float* ws  = (float*)d_ws;
  float* out = (float*)d_out;

  if (ws_size < (size_t)WS_FLOATS * sizeof(float)) return;

  {
    int total = N_WCT + N_TH + N_BAR + 8*NSTEP;
    prep_a<<<(total + 255) / 256, 256, 0, stream>>>(Wbuf, Ws1, Ws2, trans, ws);
  }
  {
    int total = N_WEB + N_WTB + N_WTR;
    prep_b<<<(total + 255) / 256, 256, 0, stream>>>(Wih, Whh, Wl, Wr, Wtrk, ws);
  }
  (void)hipFuncSetAttribute((const void*)spinn_kernel,
                            hipFuncAttributeMaxDynamicSharedMemorySize, 160000);
  spinn_kernel<<<256, 1024, LDS_FLOATS * sizeof(float), stream>>>(
      bufs, Wtrans, btrans, bredv, ws, out);
}

// Round 10
// 18882.169 us; speedup vs baseline: 9.1424x; 1.0256x over previous
//
#include <hip/hip_runtime.h>

// =====================================================================
// SPINN-style stack LSTM, MI355X.
// 8 groups (one per XCD via HW_REG_XCC_ID) x 16 batch; 32 blocks/group.
// R10 = R9 with ONE fix: pin waves/EU to exactly 4.
// R9 post-mortem: __launch_bounds__(1024,4) is only a MINIMUM — the
// allocator targeted 8 waves/EU (64-VGPR budget) and spilled wreg to
// scratch (VGPR=64, FETCH 8.6GB = 16.8MB/step weight re-read, 50ms cold
// first dispatch). LDS caps residency at 1 block/CU = 4 waves/EU anyway,
// so amdgpu_waves_per_eu(4,4) gives the full 128-VGPR budget: wreg(40)
// stays resident. Work split: 1 dot x 40k per thread (E: 960 thr,
// T: 1000 thr), P2 k-split 4-way. Barrier: R2/R7 volatile+L1-inv
// (R8 D1 measured <0.5us/pair). fp32 throughout (absmax 9.8e-4).
// =====================================================================

#define NSTEP 511
#define HB 128
#define SQ 256
#define HD 300
#define DW 600
#define TK 64

#define NB 16
#define NE 25           // E blocks per group
#define JPB 12          // j dims per E block
#define DOTS_E 60       // 5 gates * 12 j
#define KE 640          // padded 600
#define UPB 10
#define DOTS_T 40       // 4 gates * 10 units
#define KT2 1000        // padded 964 (900 fused + 64 hh + 36 zero)
#define ASTR 20         // act row stride (floats), 16 slots + pad
#define SLP 820         // act slice pitch = 41 rows * ASTR
#define OUTW 1322

// ---- workspace layout (floats) ----
#define N_WEB 960000            // 25*60*640   E weight slices fp32
#define N_WTB 280000            // 7*40*1000   T fused weight slices fp32
#define N_WTR 97500             // 25*60*65    W_track slices
#define N_TH  16384             // 2*128*64    th double buffer
#define N_STACK 19660800        // 128*256*600
#define N_BAR 1024
#define N_TPK 4096
#define N_WCT 230400            // WcatT (prep only, overlaps stack)

#define OFF_WEB 0
#define OFF_WTB 960000
#define OFF_WTR 1240000
#define OFF_TH  1337504
#define OFF_STACK 1353888
#define OFF_BAR 21014688
#define OFF_TPK 21015712
#define WS_FLOATS 21019808
#define OFF_WCT OFF_STACK

// ---- LDS layout (floats) ----
#define L_ACT 0                 // 25 slices * SLP = 20500
#define L_DUMP 20500            // E: 8*EDP=7712 ; T: 25*TDP=16100
#define EDP 964                 // E dump kq pitch (60*16 + 4 skew)
#define TDP 644                 // T dump kq pitch (40*16 + 4 skew)
#define L_WTR 28212             // (E only) 60*65 = 3900
#define L_THL 32112             // 16*65 = 1040
#define L_BRED 33152            // 60(+pad)
#define L_TRW 36600             // 511 ints (+1)
#define L_INT 37112             // 96 ints
#define LDS_FLOATS 37208        // 148832 B (>80KB => 1 block/CU)

__device__ __forceinline__ float sigf(float x) { return 1.0f / (1.0f + __expf(-x)); }

// ---------------------------------------------------------------------
// prep_a: WcatT[256][900], zero th/barrier, pack transitions.
// ---------------------------------------------------------------------
__global__ void prep_a(const float* __restrict__ Wbuf, const float* __restrict__ Ws1,
                       const float* __restrict__ Ws2, const int* __restrict__ trans,
                       float* __restrict__ ws) {
  int idx = blockIdx.x * 256 + threadIdx.x;
  if (idx < N_WCT) {
    int k = idx % 900;
    int m = idx / 900;
    float v = (k < 300) ? Wbuf[k*256 + m]
            : (k < 600) ? Ws1[(k-300)*256 + m]
                        : Ws2[(k-600)*256 + m];
    ws[OFF_WCT + idx] = v;
    return;
  }
  idx -= N_WCT;
  if (idx < N_TH) { ws[OFF_TH + idx] = 0.0f; return; }
  idx -= N_TH;
  if (idx < N_BAR) { ws[OFF_BAR + idx] = 0.0f; return; }
  idx -= N_BAR;
  if (idx < 8*NSTEP) {
    int g = idx / NSTEP, t = idx % NSTEP;
    int w = 0;
    #pragma unroll
    for (int b = 0; b < 16; ++b)
      w |= (trans[(size_t)(g*16 + b)*NSTEP + t] & 1) << b;
    ((int*)(ws + OFF_TPK))[g*NSTEP + t] = w;
  }
}

// ---------------------------------------------------------------------
// prep_b: fp32 transposed weight slices; tracker input projection fused
// with W_ih: WT[col][k<900] = sum_m Wcat[k][m] * W_ih[col][m]  (exact).
// ---------------------------------------------------------------------
__global__ void prep_b(const float* __restrict__ Wih, const float* __restrict__ Whh,
                       const float* __restrict__ Wl, const float* __restrict__ Wr,
                       const float* __restrict__ Wtrk, float* __restrict__ ws) {
  int idx = blockIdx.x * 256 + threadIdx.x;
  if (idx < N_WEB) {
    int k = idx % KE; int rest = idx / KE;
    int dot = rest % DOTS_E; int e = rest / DOTS_E;
    int g = dot / JPB, jj = dot % JPB;
    int col = g*HD + e*JPB + jj;
    float v = 0.0f;
    if (k < 300)      v = Wl[k*1500 + col];
    else if (k < 600) v = Wr[(k-300)*1500 + col];
    ws[OFF_WEB + idx] = v;
    return;
  }
  idx -= N_WEB;
  if (idx < N_WTB) {
    int k = idx % KT2; int rest = idx / KT2;
    int dot = rest % DOTS_T; int tb = rest / DOTS_T;
    int g = dot / UPB, uu = dot % UPB;
    int ucnt = (tb == 6) ? 10 : 9;
    float v = 0.0f;
    if (uu < ucnt) {
      int col = g*TK + tb*9 + uu;
      if (k < 900) {
        const float* wct = ws + OFF_WCT;
        const float* wi  = Wih + col*256;
        float s = 0.0f;
        #pragma unroll 4
        for (int m = 0; m < 256; ++m) s = fmaf(wct[m*900 + k], wi[m], s);
        v = s;
      } else if (k < 964) {
        v = Whh[col*TK + (k - 900)];
      }
    }
    ws[OFF_WTB + idx] = v;
    return;
  }
  idx -= N_WTB;
  if (idx < N_WTR) {
    int k = idx % 65; int rest = idx / 65;
    int dot = rest % DOTS_E; int e = rest / DOTS_E;
    int g = dot / JPB, jj = dot % JPB;
    ws[OFF_WTR + idx] = (k < 64) ? Wtrk[k*1500 + (g*HD + e*JPB + jj)] : 0.0f;
  }
}

// ---------------------------------------------------------------------
// fence-free XCD-local barrier (R2/R7 design; R8 D1 measured <0.5us/pair).
// ---------------------------------------------------------------------
__device__ __forceinline__ void xbar(int role, unsigned epoch,
                                     volatile unsigned* slots, volatile unsigned* flag,
                                     volatile int* broken) {
  __syncthreads();                      // drains vmcnt on every wave
  if (role == 0) {
    if (threadIdx.x < 64) {
      int lane = threadIdx.x;
      unsigned spins = 0;
      for (;;) {
        if (*broken) break;
        unsigned v = (lane >= 1 && lane < 32) ? slots[lane] : epoch;
        if (__all(v >= epoch)) break;
        __builtin_amdgcn_s_sleep(1);
        asm volatile("buffer_inv" ::: "memory");
        if (++spins > 2000000u) { if (lane == 0) *broken = 1; break; }
      }
      if (lane == 0) {
        *flag = epoch;
        asm volatile("s_waitcnt vmcnt(0)" ::: "memory");
      }
    }
  } else if (threadIdx.x == 0) {
    slots[role] = epoch;
    asm volatile("s_waitcnt vmcnt(0)" ::: "memory");
    unsigned spins = 0;
    while (!*broken && *flag < epoch) {
      __builtin_amdgcn_s_sleep(1);
      asm volatile("buffer_inv" ::: "memory");
      if (++spins > 2000000u) *broken = 1;
    }
  }
  __syncthreads();
  asm volatile("buffer_inv" ::: "memory");
}

// ---------------------------------------------------------------------
// main persistent kernel: 256 blocks x 1024 threads, 1 block/CU (LDS),
// EXACTLY 4 waves/EU (pinned) -> 128-VGPR budget, wreg stays resident.
// ---------------------------------------------------------------------
__attribute__((amdgpu_flat_work_group_size(1024, 1024)))
__attribute__((amdgpu_waves_per_eu(4, 4)))
__global__ void spinn_kernel(const float* __restrict__ bufs,
                             const float* __restrict__ Wtrans, const float* __restrict__ btrans,
                             const float* __restrict__ bredv,
                             float* __restrict__ ws, float* __restrict__ out) {
  extern __shared__ float lds[];
  int* ibuf = (int*)(lds + L_INT);
  int* redl = ibuf + 16;
  int* shl  = ibuf + 32;
  int* sptr = ibuf + 48;
  int* bptr = ibuf + 64;
  volatile int* broken = ibuf + 82;
  int* role_s = ibuf + 90;
  int* trw = (int*)(lds + L_TRW);

  const int tid = threadIdx.x;

  // ---- runtime XCD-local grouping (one-time) ----
  unsigned xcc;
  asm volatile("s_getreg_b32 %0, hwreg(HW_REG_XCC_ID)" : "=s"(xcc));
  xcc &= 7u;
  if (tid == 0) {
    unsigned slot = __hip_atomic_fetch_add((unsigned*)(ws + OFF_BAR) + 512 + xcc, 1u,
                                           __ATOMIC_RELAXED, __HIP_MEMORY_SCOPE_AGENT);
    *role_s = (int)slot;
    *broken = 0;
  }
  __syncthreads();
  const int role = *role_s;
  const int group = (int)xcc;
  if (role >= 32) return;

  const int b0 = group * NB;
  const bool isE = (role < NE);
  const int e  = role;
  const int tb = role - NE;
  const int u0 = (tb >= 0) ? tb*9 : 0;
  const int ucnt = (tb == 6) ? 10 : 9;

  volatile unsigned* slots = (volatile unsigned*)((unsigned*)(ws + OFF_BAR) + (size_t)group*64);
  volatile unsigned* flag  = slots + 32;

  float* stack = ws + OFF_STACK;
  float* thbuf = ws + OFF_TH;

  float tc_reg = 0.0f;

  // ---- preload this thread's fp32 weight slice: 1 dot x 40 k = 40 VGPRs ----
  float4 wreg[10];
  if (isE) {
    if (tid < 960) {
      const int q = tid >> 4, kq = tid & 15;       // q = dot 0..59
      const float* wb = ws + OFF_WEB + (size_t)(e*DOTS_E + q)*KE + kq*40;
      #pragma unroll
      for (int i = 0; i < 10; ++i) wreg[i] = *(const float4*)(wb + 4*i);
    }
  } else {
    if (tid < 1000) {
      const int q = tid / 25, kq = tid % 25;       // q = dot 0..39
      const float* wb = ws + OFF_WTB + (size_t)(tb*DOTS_T + q)*KT2 + kq*40;
      #pragma unroll
      for (int i = 0; i < 10; ++i) wreg[i] = *(const float4*)(wb + 4*i);
    }
  }

  // ---- one-time init ----
  if (tid < 16) { sptr[tid] = 0; bptr[tid] = 0; }
  for (int i = tid; i < NSTEP; i += 1024)
    trw[i] = ((const int*)(ws + OFF_TPK))[group*NSTEP + i];
  if (isE) {
    for (int i = tid; i < DOTS_E*65; i += 1024)
      lds[L_WTR + i] = ws[OFF_WTR + (size_t)e*DOTS_E*65 + i];
    for (int i = tid; i < DOTS_E; i += 1024)
      lds[L_BRED + i] = bredv[(i/JPB)*HD + e*JPB + (i%JPB)];
    for (int i = tid; i < 800; i += 1024) lds[615*ASTR + i] = 0.0f;   // k 600..639
  } else {
    for (int i = tid; i < 720; i += 1024) lds[988*ASTR + i] = 0.0f;   // k 964..999
  }
  __syncthreads();

  unsigned epoch = 0;

  for (int t = 0; t < NSTEP; ++t) {
    // ---- prologue: transition word + compact lists ----
    const int w = trw[t] & 0xFFFF;          // bit=1 -> reduce
    const int nred = __popc(w);
    if (tid < 16) {
      int rank = __popc(w & ((1u << tid) - 1u));
      if ((w >> tid) & 1) redl[rank] = tid; else shl[tid - rank] = tid;
    }
    __syncthreads();

    // ---- P1 staging into LDS (row(k) = (k/40)*41 + k%40) ----
    if (isE) {
      int r = tid >> 6, lane = tid & 63;
      if (r < nred) {
        int b = redl[r];
        int sp = sptr[b];
        const float* s2p = stack + ((size_t)((b0+b)*SQ + sp-2))*DW;
        const float* s1p = stack + ((size_t)((b0+b)*SQ + sp-1))*DW;
        #pragma unroll
        for (int i = 0; i < 3; ++i) {
          int ch = lane + 64*i;
          if (ch < 150) {
            int sec = ch / 75, kc = ch % 75;
            int dim = kc*4;
            const float* src = (sec == 0) ? s2p : s1p;
            float4 v = *(const float4*)(src + dim);
            int kbase = sec*300 + dim;
            int row0 = (kbase/40)*41 + (kbase%40);
            lds[(row0+0)*ASTR + r] = v.x;
            lds[(row0+1)*ASTR + r] = v.y;
            lds[(row0+2)*ASTR + r] = v.z;
            lds[(row0+3)*ASTR + r] = v.w;
          }
        }
      }
    } else {
      {
        int b = tid >> 6, lane = tid & 63;
        int bp = bptr[b]; if (bp > SQ-1) bp = SQ-1;
        int sp = sptr[b];
        const float* bsrc = bufs + ((size_t)((b0+b)*SQ + bp))*DW;
        const float* s1p = (sp >= 1) ? stack + ((size_t)((b0+b)*SQ + sp-1))*DW : nullptr;
        const float* s2p = (sp >= 2) ? stack + ((size_t)((b0+b)*SQ + sp-2))*DW : nullptr;
        #pragma unroll
        for (int i = 0; i < 4; ++i) {
          int ch = lane + 64*i;
          if (ch < 225) {
            int sec = ch / 75, kc = ch % 75;
            int dim = kc*4;
            const float* src = (sec == 0) ? bsrc : ((sec == 1) ? s1p : s2p);
            float4 v = make_float4(0.f, 0.f, 0.f, 0.f);
            if (src) v = *(const float4*)(src + dim);
            int kbase = sec*300 + dim;
            int row0 = (kbase/40)*41 + (kbase%40);
            lds[(row0+0)*ASTR + b] = v.x;
            lds[(row0+1)*ASTR + b] = v.y;
            lds[(row0+2)*ASTR + b] = v.z;
            lds[(row0+3)*ASTR + b] = v.w;
          }
        }
      }
      if (tid < 256) {   // th(t-1) -> k 900..963 ; t=0 reads zeroed parity-1
        int pm = (t - 1) & 1;
        int b = tid >> 4, uc = tid & 15;
        float4 v = *(const float4*)(thbuf + ((size_t)pm*HB + (b0+b))*TK + uc*4);
        float vv[4] = {v.x, v.y, v.z, v.w};
        #pragma unroll
        for (int l = 0; l < 4; ++l) {
          int k = 900 + uc*4 + l;
          int row = (k/40)*41 + (k%40);
          lds[row*ASTR + b] = vv[l];
        }
      }
    }
    __syncthreads();

    // ---- P1 compute (1 dot/thread, weights in VGPRs, acc[4]/chunk) ----
    if (isE) {
      const int nchunk = (nred + 3) >> 2;
      if (nchunk > 0) {
        if (tid < 960) {
          const int q = tid >> 4, kq = tid & 15;
          const float* ab = lds + kq*SLP;
          float* dmp = lds + L_DUMP;
          #pragma unroll 1
          for (int c = 0; c < nchunk; ++c) {
            float a0 = 0.f, a1 = 0.f, a2 = 0.f, a3 = 0.f;
            #pragma unroll
            for (int i = 0; i < 10; ++i) {
              #pragma unroll
              for (int kk = 0; kk < 4; ++kk) {
                float4 a = *(const float4*)(ab + (4*i + kk)*ASTR + 4*c);
                float wv = (kk == 0) ? wreg[i].x : (kk == 1) ? wreg[i].y
                         : (kk == 2) ? wreg[i].z : wreg[i].w;
                a0 = fmaf(wv, a.x, a0);
                a1 = fmaf(wv, a.y, a1);
                a2 = fmaf(wv, a.z, a2);
                a3 = fmaf(wv, a.w, a3);
              }
            }
            a0 += __shfl_xor(a0, 8, 64);
            a1 += __shfl_xor(a1, 8, 64);
            a2 += __shfl_xor(a2, 8, 64);
            a3 += __shfl_xor(a3, 8, 64);
            if (kq < 8)
              *(float4*)(dmp + kq*EDP + q*16 + 4*c) = make_float4(a0, a1, a2, a3);
          }
        }
        __syncthreads();
        for (int task = tid; task < DOTS_E*16; task += 1024) {
          int dot = task >> 4, s = task & 15;
          float sum = 0.0f;
          #pragma unroll
          for (int kq = 0; kq < 8; ++kq)
            sum += lds[L_DUMP + kq*EDP + dot*16 + s];
          lds[L_DUMP + dot*16 + s] = sum;   // compact a_red
        }
      }
    } else {
      if (tid < 1000) {
        const int q = tid / 25, kq = tid % 25;
        const float* ab = lds + kq*SLP;
        float* dmp = lds + L_DUMP + kq*TDP;
        #pragma unroll 1
        for (int c = 0; c < 4; ++c) {
          float a0 = 0.f, a1 = 0.f, a2 = 0.f, a3 = 0.f;
          #pragma unroll
          for (int i = 0; i < 10; ++i) {
            #pragma unroll
            for (int kk = 0; kk < 4; ++kk) {
              float4 a = *(const float4*)(ab + (4*i + kk)*ASTR + 4*c);
              float wv = (kk == 0) ? wreg[i].x : (kk == 1) ? wreg[i].y
                       : (kk == 2) ? wreg[i].z : wreg[i].w;
              a0 = fmaf(wv, a.x, a0);
              a1 = fmaf(wv, a.y, a1);
              a2 = fmaf(wv, a.z, a2);
              a3 = fmaf(wv, a.w, a3);
            }
          }
          *(float4*)(dmp + q*16 + 4*c) = make_float4(a0, a1, a2, a3);
        }
      }
      __syncthreads();
      for (int task = tid; task < DOTS_T*16; task += 1024) {
        int dot = task >> 4, s = task & 15;
        float sum = 0.0f;
        #pragma unroll
        for (int kq = 0; kq < 25; ++kq)
          sum += lds[L_DUMP + kq*TDP + dot*16 + s];
        lds[L_DUMP + dot*16 + s] = sum;     // compact gates
      }
      __syncthreads();
      if (tid < 160) {
        int uu = tid >> 4, b = tid & 15;
        if (uu < ucnt) {
          float gi = lds[L_DUMP + (0*UPB + uu)*16 + b];
          float gf = lds[L_DUMP + (1*UPB + uu)*16 + b];
          float gg = lds[L_DUMP + (2*UPB + uu)*16 + b];
          float go = lds[L_DUMP + (3*UPB + uu)*16 + b];
          tc_reg = sigf(gf)*tc_reg + sigf(gi)*tanhf(gg);
          float th = sigf(go)*tanhf(tc_reg);
          thbuf[((size_t)(t & 1)*HB + (b0 + b))*TK + (u0 + uu)] = th;
        }
      }
    }

    ++epoch;
    xbar(role, epoch, slots, flag, broken);   // th(t) visible

    // ---- P2 (k-split 4-way: thread = (rr, jj, ks)) ----
    if (isE) {
      int p = t & 1;
      if (tid < 256) {
        int r = tid >> 4, lane = tid & 15;
        if (r < nred) {
          const float* thp = thbuf + ((size_t)p*HB + (b0 + redl[r]))*TK;
          #pragma unroll
          for (int i = 0; i < 4; ++i) {
            int k = lane + 16*i;
            lds[L_THL + r*65 + k] = thp[k];
          }
        }
      }
      __syncthreads();
      if (tid < 768) {
        int rr = tid / 48, rem = tid % 48;
        int jj = rem >> 2, ks = rem & 3;
        int j = e*JPB + jj;
        if (rr < nred) {
          int b = redl[rr];
          int sp = sptr[b];
          float* s2base = stack + ((size_t)((b0+b)*SQ + (sp-2)))*DW;
          const float* s1base = stack + ((size_t)((b0+b)*SQ + (sp-1)))*DW;
          float a0 = 0.f, a1 = 0.f, a2 = 0.f, a3 = 0.f, a4 = 0.f;
          const float* thl = lds + L_THL + rr*65 + ks*16;
          const float* w0 = lds + L_WTR + (0*JPB + jj)*65 + ks*16;
          const float* w1 = lds + L_WTR + (1*JPB + jj)*65 + ks*16;
          const float* w2 = lds + L_WTR + (2*JPB + jj)*65 + ks*16;
          const float* w3 = lds + L_WTR + (3*JPB + jj)*65 + ks*16;
          const float* w4 = lds + L_WTR + (4*JPB + jj)*65 + ks*16;
          #pragma unroll
          for (int k = 0; k < 16; ++k) {
            float tv = thl[k];
            a0 = fmaf(tv, w0[k], a0);
            a1 = fmaf(tv, w1[k], a1);
            a2 = fmaf(tv, w2[k], a2);
            a3 = fmaf(tv, w3[k], a3);
            a4 = fmaf(tv, w4[k], a4);
          }
          a0 += __shfl_xor(a0, 1, 64); a0 += __shfl_xor(a0, 2, 64);
          a1 += __shfl_xor(a1, 1, 64); a1 += __shfl_xor(a1, 2, 64);
          a2 += __shfl_xor(a2, 1, 64); a2 += __shfl_xor(a2, 2, 64);
          a3 += __shfl_xor(a3, 1, 64); a3 += __shfl_xor(a3, 2, 64);
          a4 += __shfl_xor(a4, 1, 64); a4 += __shfl_xor(a4, 2, 64);
          if (ks == 0) {
            a0 += lds[L_DUMP + (0*JPB + jj)*16 + rr] + lds[L_BRED + 0*JPB + jj];
            a1 += lds[L_DUMP + (1*JPB + jj)*16 + rr] + lds[L_BRED + 1*JPB + jj];
            a2 += lds[L_DUMP + (2*JPB + jj)*16 + rr] + lds[L_BRED + 2*JPB + jj];
            a3 += lds[L_DUMP + (3*JPB + jj)*16 + rr] + lds[L_BRED + 3*JPB + jj];
            a4 += lds[L_DUMP + (4*JPB + jj)*16 + rr] + lds[L_BRED + 4*JPB + jj];
            float s2c = s2base[HD + j];
            float s1c = s1base[HD + j];
            float rc = sigf(a1)*s2c + sigf(a2)*s1c + sigf(a0)*tanhf(a4);
            float rh = sigf(a3)*tanhf(rc);
            s2base[j] = rh;
            s2base[HD + j] = rc;
          }
        } else {   // shift: copy buf top -> stack[sp] (ks 0/1 split h/c)
          int b = shl[rr - nred];
          int sp = sptr[b], bp = bptr[b];
          const float* src = bufs + ((size_t)((b0+b)*SQ + bp))*DW;
          float* dst = stack + ((size_t)((b0+b)*SQ + sp))*DW;
          if (ks == 0) dst[j] = src[j];
          else if (ks == 1) dst[HD + j] = src[HD + j];
        }
      }
    } else if (role == NE) {   // logits
      if (tid < 32) {
        int b = tid >> 1, c = tid & 1;
        const float* th = thbuf + ((size_t)(t & 1)*HB + (b0 + b))*TK;
        float s = btrans[c];
        #pragma unroll 8
        for (int u = 0; u < TK; ++u) s = fmaf(th[u], Wtrans[u*2 + c], s);
        out[(size_t)(b0 + b)*OUTW + HD + 2*t + c] = s;
      }
    }

    __syncthreads();
    if (tid < 16) {
      if (!((w >> tid) & 1)) { sptr[tid] += 1; bptr[tid] += 1; }
      else                   { sptr[tid] -= 1; }
    }

    ++epoch;
    xbar(role, epoch, slots, flag, broken);   // stack(t) visible
  }

  // ---- final sentence encoding ----
  if (isE && tid < 192) {
    int b = tid / JPB, jj = tid % JPB;
    int j = e*JPB + jj;
    int sp = sptr[b] - 1; if (sp < 0) sp = 0;
    out[(size_t)(b0 + b)*OUTW + j] =
        stack[((size_t)((b0 + b)*SQ + sp))*DW + j];
  }
}

// ---------------------------------------------------------------------
extern "C" void kernel_launch(void* const* d_in, const int* in_sizes, int n_in,
                              void* d_out, int out_size, void* d_ws, size_t ws_size,
                              hipStream_t stream) {
  const float* bufs   = (const float*)d_in[0];
  const int*   trans  = (const int*)  d_in[1];
  const float* Wbuf   = (const float*)d_in[2];
  const float* Ws1    = (const float*)d_in[3];
  const float* Ws2    = (const float*)d_in[4];
  const float* Wih    = (const float*)d_in[5];
  const float* Whh    = (const float*)d_in[6];
  const float* Wtrans = (const float*)d_in[7];
  const float* btrans = (const float*)d_in[8];
  const float* Wl     = (const float*)d_in[9];
  const float* Wr     = (const float*)d_in[10];
  const float* Wtrk   = (const float*)d_in[11];
  const float* bredv  = (const float*)d_in[12];
  float* ws  = (float*)d_ws;
  float* out = (float*)d_out;

  if (ws_size < (size_t)WS_FLOATS * sizeof(float)) return;

  {
    int total = N_WCT + N_TH + N_BAR + 8*NSTEP;
    prep_a<<<(total + 255) / 256, 256, 0, stream>>>(Wbuf, Ws1, Ws2, trans, ws);
  }
  {
    int total = N_WEB + N_WTB + N_WTR;
    prep_b<<<(total + 255) / 256, 256, 0, stream>>>(Wih, Whh, Wl, Wr, Wtrk, ws);
  }
  (void)hipFuncSetAttribute((const void*)spinn_kernel,
                            hipFuncAttributeMaxDynamicSharedMemorySize, 160000);
  spinn_kernel<<<256, 1024, LDS_FLOATS * sizeof(float), stream>>>(
      bufs, Wtrans, btrans, bredv, ws, out);
}